// Round 7
// baseline (95.070 us; speedup 1.0000x reference)
//
#include <hip/hip_runtime.h>

// Problem constants (match the JAX reference)
constexpr int Bv  = 4;
constexpr int NXv = 432;
constexpr int NYv = 496;
constexpr int Cv  = 64;
constexpr int PLANE = NYv * NXv;          // 214272 cells per (b) grid
constexpr int GRID_CELLS = Bv * PLANE;    // 857088 cells per tensor
constexpr int PER_TENSOR_T4 = GRID_CELLS / 4;  // 214272 threads per tensor (4 cells each)

typedef float v4f __attribute__((ext_vector_type(4)));

__device__ __constant__ float ZROW[Cv] = {};   // all zeros: fallback row for empty cells

// ---------------------------------------------------------------------------
// Kernel 1: fused scatter of per-batch-LOCAL voxel index into uint16 map for
// both tensors. Sentinel = 0xFFFF (map memset to 0xFF). Local idx <= 16383.
// coords row layout: (b, z, y, x), z == 0; rows are batch-major so
// local = i - b*per_batch.
// ---------------------------------------------------------------------------
__global__ void build_all_kernel(const int* __restrict__ t_coords, int nt, int ptb,
                                 const int* __restrict__ s_coords, int ns, int psb,
                                 unsigned short* __restrict__ map) {
    int i = blockIdx.x * blockDim.x + threadIdx.x;
    if (i < nt) {
        const int4 c = reinterpret_cast<const int4*>(t_coords)[i]; // b,z,y,x
        map[(c.x * NYv + c.z) * NXv + c.w] = (unsigned short)(i - c.x * ptb);
    } else if (i < nt + ns) {
        int j = i - nt;
        const int4 c = reinterpret_cast<const int4*>(s_coords)[j];
        map[GRID_CELLS + (c.x * NYv + c.z) * NXv + c.w] = (unsigned short)(j - c.x * psb);
    }
}

// ---------------------------------------------------------------------------
// Kernel 2: fused gather for BOTH output tensors.
// One thread per 4 consecutive x-cells; 4 chunks of 16 channels
// (batch-load 64B runs, then 16 transposed nontemporal 1KB-coalesced stores).
// uint16 map entries are per-batch-local rows; b is wave-uniform.
// ---------------------------------------------------------------------------
__global__ __launch_bounds__(256, 4) void gather_all_kernel(
        const unsigned short* __restrict__ map,
        const float* __restrict__ t_feats,
        const float* __restrict__ s_feats,
        int ptb, int psb,
        float* __restrict__ out, size_t half) {
    int tid = blockIdx.x * blockDim.x + threadIdx.x;
    const int which = (tid >= PER_TENSOR_T4) ? 1 : 0;  // wave-uniform (214272 % 64 == 0)
    const int lid = tid - which * PER_TENSOR_T4;

    const unsigned short* mp = map + which * GRID_CELLS;
    const float* feats = which ? s_feats : t_feats;
    const int    pb    = which ? psb : ptb;
    float*       obase = out + (which ? half : 0);

    const int g = lid * 4;                 // first cell index (b*PLANE + y*NX + x)
    const int b = lid / (PLANE / 4);       // wave-uniform (53568 % 64 == 0)

    const ushort4 m = *reinterpret_cast<const ushort4*>(mp + g);
    const bool occ = (m.x & m.y & m.z & m.w) != 0xFFFF;  // all-sentinel iff AND==0xFFFF

    const size_t rowbase = (size_t)b * pb;
    const float* p0 = (m.x != 0xFFFF) ? feats + (rowbase + m.x) * Cv : ZROW;
    const float* p1 = (m.y != 0xFFFF) ? feats + (rowbase + m.y) * Cv : ZROW;
    const float* p2 = (m.z != 0xFFFF) ? feats + (rowbase + m.z) * Cv : ZROW;
    const float* p3 = (m.w != 0xFFFF) ? feats + (rowbase + m.w) * Cv : ZROW;

    // out[b][c][y][x]: offset = g + b*(Cv-1)*PLANE + c*PLANE
    float* o = obase + g + (size_t)b * (Cv - 1) * PLANE;

    #pragma unroll 1
    for (int ch = 0; ch < 4; ++ch) {       // 16 channels per chunk
        const int cb = ch * 16;
        v4f r0[4], r1[4], r2[4], r3[4];
        #pragma unroll
        for (int j = 0; j < 4; ++j) {
            r0[j] = (v4f){0.f, 0.f, 0.f, 0.f};
            r1[j] = (v4f){0.f, 0.f, 0.f, 0.f};
            r2[j] = (v4f){0.f, 0.f, 0.f, 0.f};
            r3[j] = (v4f){0.f, 0.f, 0.f, 0.f};
        }
        if (occ) {  // divergent region contains ONLY loads
            #pragma unroll
            for (int j = 0; j < 4; ++j) {
                r0[j] = *reinterpret_cast<const v4f*>(p0 + cb + j * 4);
                r1[j] = *reinterpret_cast<const v4f*>(p1 + cb + j * 4);
                r2[j] = *reinterpret_cast<const v4f*>(p2 + cb + j * 4);
                r3[j] = *reinterpret_cast<const v4f*>(p3 + cb + j * 4);
            }
        }
        // full-wave store phase: 16 transposed nontemporal stores
        #pragma unroll
        for (int j = 0; j < 4; ++j) {
            const v4f s0 = {r0[j].x, r1[j].x, r2[j].x, r3[j].x};
            const v4f s1 = {r0[j].y, r1[j].y, r2[j].y, r3[j].y};
            const v4f s2 = {r0[j].z, r1[j].z, r2[j].z, r3[j].z};
            const v4f s3 = {r0[j].w, r1[j].w, r2[j].w, r3[j].w};
            __builtin_nontemporal_store(s0, reinterpret_cast<v4f*>(o + (size_t)(cb + j * 4 + 0) * PLANE));
            __builtin_nontemporal_store(s1, reinterpret_cast<v4f*>(o + (size_t)(cb + j * 4 + 1) * PLANE));
            __builtin_nontemporal_store(s2, reinterpret_cast<v4f*>(o + (size_t)(cb + j * 4 + 2) * PLANE));
            __builtin_nontemporal_store(s3, reinterpret_cast<v4f*>(o + (size_t)(cb + j * 4 + 3) * PLANE));
        }
    }
}

// ---------------------------------------------------------------------------
// Fallback (only if ws too small): direct scatter after zeroing output.
// ---------------------------------------------------------------------------
__global__ void direct_scatter_kernel(const float* __restrict__ feats,
                                      const int* __restrict__ coords, int n,
                                      float* __restrict__ out) {
    int i = blockIdx.x * blockDim.x + threadIdx.x;
    if (i >= n * Cv) return;
    int v = i >> 6;
    int c = i & 63;
    int b = coords[v * 4 + 0];
    int y = coords[v * 4 + 2];
    int x = coords[v * 4 + 3];
    out[((size_t)(b * Cv + c) * NYv + y) * NXv + x] = feats[(size_t)v * Cv + c];
}

extern "C" void kernel_launch(void* const* d_in, const int* in_sizes, int n_in,
                              void* d_out, int out_size, void* d_ws, size_t ws_size,
                              hipStream_t stream) {
    const float* t_feats  = (const float*)d_in[0];
    const int*   t_coords = (const int*)d_in[1];
    const float* s_feats  = (const float*)d_in[2];
    const int*   s_coords = (const int*)d_in[3];
    float* out = (float*)d_out;

    const int NT = in_sizes[0] / Cv;  // 16384 template voxels
    const int NS = in_sizes[2] / Cv;  // 65536 search voxels
    const int ptb = NT / Bv;          // 4096 per batch
    const int psb = NS / Bv;          // 16384 per batch
    const size_t half = (size_t)out_size / 2;

    const size_t map_bytes = 2ull * GRID_CELLS * sizeof(unsigned short);  // 3.43 MB

    if (ws_size >= map_bytes) {
        unsigned short* map = (unsigned short*)d_ws;

        // One memset: maps -> 0xFFFF (sentinel)
        (void)hipMemsetAsync(d_ws, 0xFF, map_bytes, stream);

        build_all_kernel<<<(NT + NS + 255) / 256, 256, 0, stream>>>(
            t_coords, NT, ptb, s_coords, NS, psb, map);

        const int gthreads = 2 * PER_TENSOR_T4;            // 428544
        gather_all_kernel<<<gthreads / 256, 256, 0, stream>>>(
            map, t_feats, s_feats, ptb, psb, out, half);
    } else {
        (void)hipMemsetAsync(d_out, 0, (size_t)out_size * sizeof(float), stream);
        direct_scatter_kernel<<<(NT * Cv + 255) / 256, 256, 0, stream>>>(
            t_feats, t_coords, NT, out);
        direct_scatter_kernel<<<(NS * Cv + 255) / 256, 256, 0, stream>>>(
            s_feats, s_coords, NS, out + half);
    }
}